// Round 3
// baseline (331.456 us; speedup 1.0000x reference)
//
#include <hip/hip_runtime.h>
#include <hip/hip_bf16.h>

using short8   = __attribute__((ext_vector_type(8))) short;
using floatx4  = __attribute__((ext_vector_type(4))) float;
using floatx16 = __attribute__((ext_vector_type(16))) float;

#define KDIM 768
#define QSCALE 0.18033688011112042f   // 0.125 * log2(e)
#define N1 (8192 * 768)
#define N2 (2304 * 768)
#define N3 (768 * 768)

__device__ __forceinline__ short f2bf(float f) {
    union { float f; unsigned u; } v; v.f = f;
    unsigned r = v.u + 0x7fffu + ((v.u >> 16) & 1u);
    return (short)(r >> 16);
}

__device__ __forceinline__ unsigned pack2bf(float a, float b) {
    __hip_bfloat162 h = __float22bfloat162_rn(float2{a, b});
    union { __hip_bfloat162 h; unsigned u; } c; c.h = h;
    return c.u;
}

__device__ __forceinline__ float fast_exp2(float x) {
#if __has_builtin(__builtin_amdgcn_exp2f)
    return __builtin_amdgcn_exp2f(x);
#else
    return exp2f(x);
#endif
}

__device__ __forceinline__ void async16(const void* g, void* l) {
    __builtin_amdgcn_global_load_lds((const __attribute__((address_space(1))) void*)g,
                                     (__attribute__((address_space(3))) void*)l, 16, 0, 0);
}

// ---------------- fused fp32 -> bf16 convert for all three inputs ----------------
__global__ void cvt_all(const float* __restrict__ a, const float* __restrict__ b,
                        const float* __restrict__ c, short* __restrict__ oa,
                        short* __restrict__ ob, short* __restrict__ oc) {
    int i = (blockIdx.x * blockDim.x + threadIdx.x) * 4;
    const float* src; short* dst;
    if (i < N1)            { src = a + i;            dst = oa + i; }
    else if (i < N1 + N2)  { src = b + (i - N1);     dst = ob + (i - N1); }
    else if (i < N1+N2+N3) { src = c + (i - N1 - N2); dst = oc + (i - N1 - N2); }
    else return;
    float4 v = *(const float4*)src;
    short4 o;
    o.x = f2bf(v.x); o.y = f2bf(v.y); o.z = f2bf(v.z); o.w = f2bf(v.w);
    *(short4*)dst = o;
}

// ---------------- QKV GEMM: C[8192,2304] = X @ W^T, scatter to Q/K/V [bh][s][64] ----------------
__global__ __launch_bounds__(256) void gemm_qkv(
    const short* __restrict__ X, const short* __restrict__ W,
    const float* __restrict__ bias,
    short* __restrict__ Qb, short* __restrict__ Kb, short* __restrict__ Vb)
{
    __shared__ short As[128 * 32];
    __shared__ short Bs[128 * 32];
    int tid = threadIdx.x;
    int w = tid >> 6, l = tid & 63;
    int lane16 = l & 15, quad = l >> 4;
    int wm = w & 1, wn = w >> 1;
    int m0 = blockIdx.y * 128, n0 = blockIdx.x * 128;

    floatx4 acc[4][4] = {};

    int srow = w * 32 + (l >> 2);
    int scol = (l & 3) * 8;
    const short* Xg = X + (size_t)(m0 + srow) * KDIM + scol;
    const short* Wg = W + (size_t)(n0 + srow) * KDIM + scol;
    short* AsW = As + (w * 32) * 32;
    short* BsW = Bs + (w * 32) * 32;

    for (int kb = 0; kb < KDIM; kb += 32) {
        __syncthreads();
        async16(Xg + kb,              AsW);
        async16(Xg + kb + 16 * KDIM,  AsW + 16 * 32);
        async16(Wg + kb,              BsW);
        async16(Wg + kb + 16 * KDIM,  BsW + 16 * 32);
        __syncthreads();
        short8 a[4], b[4];
#pragma unroll
        for (int mt = 0; mt < 4; mt++) a[mt] = *(const short8*)(As + (wm * 64 + mt * 16 + lane16) * 32 + quad * 8);
#pragma unroll
        for (int nt = 0; nt < 4; nt++) b[nt] = *(const short8*)(Bs + (wn * 64 + nt * 16 + lane16) * 32 + quad * 8);
#pragma unroll
        for (int mt = 0; mt < 4; mt++)
#pragma unroll
            for (int nt = 0; nt < 4; nt++)
                acc[mt][nt] = __builtin_amdgcn_mfma_f32_16x16x32_bf16(a[mt], b[nt], acc[mt][nt], 0, 0, 0);
    }

#pragma unroll
    for (int mt = 0; mt < 4; mt++) {
        int row = m0 + wm * 64 + mt * 16 + quad * 4;
#pragma unroll
        for (int nt = 0; nt < 4; nt++) {
            int col = n0 + wn * 64 + nt * 16 + lane16;
            int qkv = (col >= 1536) ? 2 : ((col >= 768) ? 1 : 0);
            int rem = col - qkv * 768;
            int h = rem >> 6, e = rem & 63;
            short* dst = (qkv == 0) ? Qb : ((qkv == 1) ? Kb : Vb);
            float sc = (qkv == 0) ? (float)QSCALE : 1.0f;
            float bv = bias[col];
#pragma unroll
            for (int r = 0; r < 4; r++) {
                int i  = row + r;
                int b_ = i >> 11, s_ = i & 2047;
                dst[(((size_t)(b_ * 12 + h)) * 2048 + s_) * 64 + e] = f2bf((acc[mt][nt][r] + bv) * sc);
            }
        }
    }
}

// ---------------- V transpose + sigma key-permute: Vb [bh][s][64] -> Vt [bh][e][64-key tiles] ----------------
__global__ __launch_bounds__(256) void transpose_v(
    const short* __restrict__ Vb, short* __restrict__ Vt)
{
    __shared__ short T[64 * 66];
    int tid = threadIdx.x;
    int s0 = blockIdx.x * 64, bh = blockIdx.y;
    const short* src = Vb + (size_t)bh * 2048 * 64;
    short* dst = Vt + (size_t)bh * 64 * 2048;

#pragma unroll
    for (int i = 0; i < 2; i++) {
        int slot = i * 256 + tid;
        int s_loc = slot >> 3, ec = slot & 7;
        short8 v = *(const short8*)(src + (size_t)(s0 + s_loc) * 64 + ec * 8);
        *(short8*)(T + s_loc * 66 + ec * 8) = v;
    }
    __syncthreads();
#pragma unroll
    for (int i = 0; i < 2; i++) {
        int slot = i * 256 + tid;
        int e_loc = slot >> 3, sc = slot & 7;
        short8 o;
#pragma unroll
        for (int j = 0; j < 8; j++) {
            int p = sc * 8 + j;
            int kp = (p & 0x33) | ((p & 4) << 1) | ((p & 8) >> 1);   // sigma: swap bits 2,3
            o[j] = T[kp * 66 + e_loc];
        }
        *(short8*)(dst + (size_t)e_loc * 2048 + s0 + sc * 8) = o;
    }
}

// ---------------- flash attention, 32x32x16 MFMA, transposed QK^T, P in registers ----------------
// grid (16,48), 256 thr / 4 waves, 32 q-rows/wave, 12 waves/CU.
// NO LDS, NO BARRIERS: K and V^T fragments load straight from global (L1/L2-resident:
// K/V per head = 256 KB each, L2-fits; 16 blocks share each bh; 4 waves/block read the
// same lines -> L1 hits). Waves run fully independent and phase-skewed, so QK / softmax /
// PV of different waves overlap on the MFMA / trans / VMEM pipes. (m169 pattern.)
__global__ __launch_bounds__(256, 3) void attn(
    const short* __restrict__ Qb, const short* __restrict__ Kb,
    const short* __restrict__ Vt, short* __restrict__ Ctx)
{
    int tid = threadIdx.x, w = tid >> 6, l = tid & 63;
    int l32 = l & 31, half = l >> 5;
    int qt = blockIdx.x, bh = blockIdx.y;
    const short* Qh  = Qb + (size_t)bh * 2048 * 64;
    const short* Kh  = Kb + (size_t)bh * 2048 * 64;
    const short* Vth = Vt + (size_t)bh * 64 * 2048;
    int qbase = qt * 128 + w * 32;

    // Q fragments (B operand): lane holds q = qbase + l32, k = e
    short8 qf[4];
#pragma unroll
    for (int ks = 0; ks < 4; ks++)
        qf[ks] = *(const short8*)(Qh + (size_t)(qbase + l32) * 64 + ks * 16 + half * 8);

    // per-lane base pointers (element offsets folded by compiler into imm offsets)
    // K fragment (A operand): row = kt*64 + nt*32 + l32, e-chunk = (ks*2+half)*8
    const short* kp = Kh + (size_t)l32 * 64 + half * 8;
    // V^T fragment (B operand): e-row = nt*32 + l32, key-chunk = kt*64 + (ks*2+half)*8
    const short* vp = Vth + (size_t)l32 * 2048 + half * 8;

    float lsum = 0.f;
    floatx16 acc[2] = {};

    for (int kt = 0; kt < 32; kt++) {
        // issue all 16 loads up front; V latency hides under QK + softmax
        short8 kf[2][4], vf[2][4];
#pragma unroll
        for (int nt = 0; nt < 2; nt++)
#pragma unroll
            for (int ks = 0; ks < 4; ks++)
                kf[nt][ks] = *(const short8*)(kp + (size_t)kt * 4096 + nt * 2048 + ks * 16);
#pragma unroll
        for (int nt = 0; nt < 2; nt++)
#pragma unroll
            for (int ks = 0; ks < 4; ks++)
                vf[nt][ks] = *(const short8*)(vp + (size_t)nt * 65536 + kt * 64 + ks * 16);

        // S^T: A = K-frag (m = key), B = Q-frag (n = q) -> col = q = l32
        floatx16 s[2];
#pragma unroll
        for (int nt = 0; nt < 2; nt++) {
            floatx16 c = {};
#pragma unroll
            for (int ks = 0; ks < 4; ks++)
                c = __builtin_amdgcn_mfma_f32_32x32x16_bf16(kf[nt][ks], qf[ks], c, 0, 0, 0);
            s[nt] = c;
        }

        // exp2 + row-sum + pack P into A-fragments in registers:
        // reg (nt, r) -> pa[2*nt + (r>>3)], element j = r&7
        union { short8 s8; unsigned u[4]; } pa[4];
#pragma unroll
        for (int nt = 0; nt < 2; nt++)
#pragma unroll
            for (int r = 0; r < 16; r += 2) {
                float p0 = fast_exp2(s[nt][r]);
                float p1 = fast_exp2(s[nt][r + 1]);
                lsum += p0 + p1;
                pa[2 * nt + (r >> 3)].u[(r & 7) >> 1] = pack2bf(p0, p1);
            }

        // PV: A = P (registers), B = V^T fragments (sigma key order baked into Vt)
#pragma unroll
        for (int nt = 0; nt < 2; nt++)
#pragma unroll
            for (int ks = 0; ks < 4; ks++)
                acc[nt] = __builtin_amdgcn_mfma_f32_32x32x16_bf16(pa[ks].s8, vf[nt][ks], acc[nt], 0, 0, 0);
    }

    // denominator for q = l32 (this lane's own q-row): combine the two halves
    float denom = lsum + __shfl_xor(lsum, 32);
    float inv_self = 1.0f / denom;

    int b_ = bh / 12, h = bh % 12;
#pragma unroll
    for (int nt = 0; nt < 2; nt++)
#pragma unroll
        for (int r = 0; r < 16; r++) {
            int qloc = (r & 3) + 8 * (r >> 2) + 4 * half;
            float invq = __shfl(inv_self, qloc);   // lane qloc holds q=qloc's inverse denom
            int q = qbase + qloc;
            int e = nt * 32 + l32;
            Ctx[((size_t)(b_ * 2048 + q)) * 768 + h * 64 + e] = f2bf(acc[nt][r] * invq);
        }
}

// ---------------- proj GEMM: out[8192,768] = Ctx @ W2^T + b, fp32 out ----------------
// Tile 64(M) x 128(N): grid 6x128 = 768 blocks = exactly 3/CU (was 384 = 1.5/CU, 33% tail waste)
__global__ __launch_bounds__(256) void gemm_out(
    const short* __restrict__ Ctx, const short* __restrict__ W,
    const float* __restrict__ bias, float* __restrict__ out)
{
    __shared__ short As[64 * 32];
    __shared__ short Bs[128 * 32];
    int tid = threadIdx.x;
    int w = tid >> 6, l = tid & 63;
    int lane16 = l & 15, quad = l >> 4;
    int wm = w & 1, wn = w >> 1;
    int m0 = blockIdx.y * 64, n0 = blockIdx.x * 128;

    floatx4 acc[2][4] = {};

    int srow = tid >> 2;        // 0..63
    int scol = (tid & 3) * 8;
    const short* Xg = Ctx + (size_t)(m0 + srow) * KDIM + scol;
    const short* Wg = W + (size_t)(n0 + srow) * KDIM + scol;
    short* AsW = As + (w * 16) * 32;
    short* BsW = Bs + (w * 16) * 32;

    for (int kb = 0; kb < KDIM; kb += 32) {
        __syncthreads();
        async16(Xg + kb,             AsW);
        async16(Wg + kb,             BsW);
        async16(Wg + kb + 64 * KDIM, BsW + 64 * 32);
        __syncthreads();
        short8 a[2], b[4];
#pragma unroll
        for (int mt = 0; mt < 2; mt++) a[mt] = *(const short8*)(As + (wm * 32 + mt * 16 + lane16) * 32 + quad * 8);
#pragma unroll
        for (int nt = 0; nt < 4; nt++) b[nt] = *(const short8*)(Bs + (wn * 64 + nt * 16 + lane16) * 32 + quad * 8);
#pragma unroll
        for (int mt = 0; mt < 2; mt++)
#pragma unroll
            for (int nt = 0; nt < 4; nt++)
                acc[mt][nt] = __builtin_amdgcn_mfma_f32_16x16x32_bf16(a[mt], b[nt], acc[mt][nt], 0, 0, 0);
    }

#pragma unroll
    for (int mt = 0; mt < 2; mt++) {
        int row = m0 + wm * 32 + mt * 16 + quad * 4;
#pragma unroll
        for (int nt = 0; nt < 4; nt++) {
            int col = n0 + wn * 64 + nt * 16 + lane16;
            float bv = bias[col];
#pragma unroll
            for (int r = 0; r < 4; r++)
                out[(size_t)(row + r) * 768 + col] = acc[mt][nt][r] + bv;
        }
    }
}

extern "C" void kernel_launch(void* const* d_in, const int* in_sizes, int n_in,
                              void* d_out, int out_size, void* d_ws, size_t ws_size,
                              hipStream_t stream) {
    const float* hs     = (const float*)d_in[0];
    const float* qkv_w  = (const float*)d_in[1];
    const float* qkv_b  = (const float*)d_in[2];
    const float* proj_w = (const float*)d_in[3];
    const float* proj_b = (const float*)d_in[4];
    float* out = (float*)d_out;

    short* Xb  = (short*)d_ws;                     // 8192*768 (dead after gemm_qkv; reused as Vt)
    short* W1b = Xb  + (size_t)8192 * 768;         // 2304*768
    short* W2b = W1b + (size_t)2304 * 768;         // 768*768
    short* Qb  = W2b + (size_t)768 * 768;          // 48*2048*64
    short* Kb  = Qb  + (size_t)8192 * 768;
    short* Vb  = Kb  + (size_t)8192 * 768;
    short* Ctx = Vb  + (size_t)8192 * 768;         // 8192*768
    short* Vt  = Xb;                               // [bh][64][2048] sigma-ordered, overlays dead Xb

    int ntot = (N1 + N2 + N3) / 4;
    cvt_all<<<(ntot + 255) / 256, 256, 0, stream>>>(hs, qkv_w, proj_w, Xb, W1b, W2b);

    gemm_qkv<<<dim3(18, 64), 256, 0, stream>>>(Xb, W1b, qkv_b, Qb, Kb, Vb);
    transpose_v<<<dim3(32, 48), 256, 0, stream>>>(Vb, Vt);
    attn<<<dim3(16, 48), 256, 0, stream>>>(Qb, Kb, Vt, Ctx);
    gemm_out<<<dim3(6, 128), 256, 0, stream>>>(Ctx, W2b, proj_b, out);
}

// Round 4
// 223.296 us; speedup vs baseline: 1.4844x; 1.4844x over previous
//
#include <hip/hip_runtime.h>
#include <hip/hip_bf16.h>

using short8   = __attribute__((ext_vector_type(8))) short;
using floatx4  = __attribute__((ext_vector_type(4))) float;
using floatx16 = __attribute__((ext_vector_type(16))) float;

#define KDIM 768
#define QSCALE 0.18033688011112042f   // 0.125 * log2(e)
#define N1 (8192 * 768)
#define N2 (2304 * 768)
#define N3 (768 * 768)

__device__ __forceinline__ short f2bf(float f) {
    union { float f; unsigned u; } v; v.f = f;
    unsigned r = v.u + 0x7fffu + ((v.u >> 16) & 1u);
    return (short)(r >> 16);
}

__device__ __forceinline__ unsigned pack2bf(float a, float b) {
    __hip_bfloat162 h = __float22bfloat162_rn(float2{a, b});
    union { __hip_bfloat162 h; unsigned u; } c; c.h = h;
    return c.u;
}

__device__ __forceinline__ float fast_exp2(float x) {
#if __has_builtin(__builtin_amdgcn_exp2f)
    return __builtin_amdgcn_exp2f(x);
#else
    return exp2f(x);
#endif
}

__device__ __forceinline__ void async16(const void* g, void* l) {
    __builtin_amdgcn_global_load_lds((const __attribute__((address_space(1))) void*)g,
                                     (__attribute__((address_space(3))) void*)l, 16, 0, 0);
}

// ---------------- fused fp32 -> bf16 convert for all three inputs ----------------
__global__ void cvt_all(const float* __restrict__ a, const float* __restrict__ b,
                        const float* __restrict__ c, short* __restrict__ oa,
                        short* __restrict__ ob, short* __restrict__ oc) {
    int i = (blockIdx.x * blockDim.x + threadIdx.x) * 4;
    const float* src; short* dst;
    if (i < N1)            { src = a + i;            dst = oa + i; }
    else if (i < N1 + N2)  { src = b + (i - N1);     dst = ob + (i - N1); }
    else if (i < N1+N2+N3) { src = c + (i - N1 - N2); dst = oc + (i - N1 - N2); }
    else return;
    float4 v = *(const float4*)src;
    short4 o;
    o.x = f2bf(v.x); o.y = f2bf(v.y); o.z = f2bf(v.z); o.w = f2bf(v.w);
    *(short4*)dst = o;
}

// ---------------- QKV GEMM: C[8192,2304] = X @ W^T, scatter to Q/K/V [bh][s][64] ----------------
// XCD-aware remap: XCD c = fid%8 owns M-rows [8c, 8c+8) -> X slice 1.5 MB + W 3.5 MB fits its L2.
__global__ __launch_bounds__(256) void gemm_qkv(
    const short* __restrict__ X, const short* __restrict__ W,
    const float* __restrict__ bias,
    short* __restrict__ Qb, short* __restrict__ Kb, short* __restrict__ Vb)
{
    __shared__ short As[128 * 32];
    __shared__ short Bs[128 * 32];
    int tid = threadIdx.x;
    int w = tid >> 6, l = tid & 63;
    int lane16 = l & 15, quad = l >> 4;
    int wm = w & 1, wn = w >> 1;

    int fid = blockIdx.x + 18 * blockIdx.y;   // 0..1151, dispatch order
    int c = fid & 7, s = fid >> 3;            // s in 0..143
    int my = c * 8 + s / 18;                  // 0..63
    int nx = s % 18;                          // 0..17
    int m0 = my * 128, n0 = nx * 128;

    floatx4 acc[4][4] = {};

    int srow = w * 32 + (l >> 2);
    int scol = (l & 3) * 8;
    const short* Xg = X + (size_t)(m0 + srow) * KDIM + scol;
    const short* Wg = W + (size_t)(n0 + srow) * KDIM + scol;
    short* AsW = As + (w * 32) * 32;
    short* BsW = Bs + (w * 32) * 32;

    for (int kb = 0; kb < KDIM; kb += 32) {
        __syncthreads();
        async16(Xg + kb,              AsW);
        async16(Xg + kb + 16 * KDIM,  AsW + 16 * 32);
        async16(Wg + kb,              BsW);
        async16(Wg + kb + 16 * KDIM,  BsW + 16 * 32);
        __syncthreads();
        short8 a[4], b[4];
#pragma unroll
        for (int mt = 0; mt < 4; mt++) a[mt] = *(const short8*)(As + (wm * 64 + mt * 16 + lane16) * 32 + quad * 8);
#pragma unroll
        for (int nt = 0; nt < 4; nt++) b[nt] = *(const short8*)(Bs + (wn * 64 + nt * 16 + lane16) * 32 + quad * 8);
#pragma unroll
        for (int mt = 0; mt < 4; mt++)
#pragma unroll
            for (int nt = 0; nt < 4; nt++)
                acc[mt][nt] = __builtin_amdgcn_mfma_f32_16x16x32_bf16(a[mt], b[nt], acc[mt][nt], 0, 0, 0);
    }

#pragma unroll
    for (int mt = 0; mt < 4; mt++) {
        int row = m0 + wm * 64 + mt * 16 + quad * 4;
#pragma unroll
        for (int nt = 0; nt < 4; nt++) {
            int col = n0 + wn * 64 + nt * 16 + lane16;
            int qkv = (col >= 1536) ? 2 : ((col >= 768) ? 1 : 0);
            int rem = col - qkv * 768;
            int h = rem >> 6, e = rem & 63;
            short* dst = (qkv == 0) ? Qb : ((qkv == 1) ? Kb : Vb);
            float sc = (qkv == 0) ? (float)QSCALE : 1.0f;
            float bv = bias[col];
#pragma unroll
            for (int r = 0; r < 4; r++) {
                int i  = row + r;
                int b_ = i >> 11, s_ = i & 2047;
                dst[(((size_t)(b_ * 12 + h)) * 2048 + s_) * 64 + e] = f2bf((acc[mt][nt][r] + bv) * sc);
            }
        }
    }
}

// ---------------- V transpose + sigma key-permute: Vb [bh][s][64] -> Vt [bh][e][64-key tiles] ----------------
__global__ __launch_bounds__(256) void transpose_v(
    const short* __restrict__ Vb, short* __restrict__ Vt)
{
    __shared__ short T[64 * 66];
    int tid = threadIdx.x;
    int s0 = blockIdx.x * 64, bh = blockIdx.y;
    const short* src = Vb + (size_t)bh * 2048 * 64;
    short* dst = Vt + (size_t)bh * 64 * 2048;

#pragma unroll
    for (int i = 0; i < 2; i++) {
        int slot = i * 256 + tid;
        int s_loc = slot >> 3, ec = slot & 7;
        short8 v = *(const short8*)(src + (size_t)(s0 + s_loc) * 64 + ec * 8);
        *(short8*)(T + s_loc * 66 + ec * 8) = v;
    }
    __syncthreads();
#pragma unroll
    for (int i = 0; i < 2; i++) {
        int slot = i * 256 + tid;
        int e_loc = slot >> 3, sc = slot & 7;
        short8 o;
#pragma unroll
        for (int j = 0; j < 8; j++) {
            int p = sc * 8 + j;
            int kp = (p & 0x33) | ((p & 4) << 1) | ((p & 8) >> 1);   // sigma: swap bits 2,3
            o[j] = T[kp * 66 + e_loc];
        }
        *(short8*)(dst + (size_t)e_loc * 2048 + s0 + sc * 8) = o;
    }
}

// ---------------- flash attention, 32x32x16 MFMA, transposed QK^T, P in registers ----------------
// grid (16,48), 256 thr / 4 waves, 32 q-rows/wave, 12 waves/CU.
// XCD-aware remap: XCD c = fid%8 owns bh range [6c, 6c+6) -> K+V+Q ~4.6 MB fits its L2,
// cutting the measured 2.8x HBM over-fetch (104 MB vs 37.7 ideal).
// T5: setprio(1) around MFMA clusters (m191: +4-7% on multi-block attn).
__global__ __launch_bounds__(256, 3) void attn(
    const short* __restrict__ Qb, const short* __restrict__ Kb,
    const short* __restrict__ Vt, short* __restrict__ Ctx)
{
    __shared__ short Ks[512 * 8];      // K tile: [key 64][e 64], natural key order, swizzled slots
    __shared__ short Vs[512 * 8];      // V^T tile: [e 64][64 sigma-ordered keys], swizzled slots
    int tid = threadIdx.x, w = tid >> 6, l = tid & 63;
    int l32 = l & 31, half = l >> 5;

    int fid = blockIdx.x + (blockIdx.y << 4);   // 0..767, dispatch order
    int c = fid & 7, sfl = fid >> 3;            // sfl in 0..95
    int bh = c * 6 + (sfl >> 4);                // XCD c owns 6 heads
    int qt = sfl & 15;

    const short* Qh  = Qb + (size_t)bh * 2048 * 64;
    const short* Kh  = Kb + (size_t)bh * 2048 * 64;
    const short* Vth = Vt + (size_t)bh * 64 * 2048;
    int qbase = qt * 128 + w * 32;

    // staging: 512 slots each over 256 threads, 2 async16 per thread per tile
    const short* kSrc[2];
    const short* vSrc[2];
    short* kDst[2];
    short* vDst[2];
#pragma unroll
    for (int i = 0; i < 2; i++) {
        int slot = i * 256 + tid;
        int row = slot >> 3;
        int g = (slot & 7) ^ (row & 7);
        kSrc[i] = Kh + (size_t)row * 64 + g * 8;        // + kt*64*64
        vSrc[i] = Vth + (size_t)row * 2048 + g * 8;     // + kt*64
        kDst[i] = Ks + (size_t)(i * 256 + w * 64) * 8;  // wave-uniform base
        vDst[i] = Vs + (size_t)(i * 256 + w * 64) * 8;
    }

    // Q fragments (B operand): lane holds q = qbase + l32, k = e
    short8 qf[4];
#pragma unroll
    for (int ks = 0; ks < 4; ks++)
        qf[ks] = *(const short8*)(Qh + (size_t)(qbase + l32) * 64 + ks * 16 + half * 8);

    float lsum = 0.f;
    floatx16 acc[2] = {};
    int sw = l32 & 7;   // row-swizzle term (row & 7 == l32 & 7 for row = nt*32 + l32)

    for (int kt = 0; kt < 32; kt++) {
        __syncthreads();
#pragma unroll
        for (int i = 0; i < 2; i++) {
            async16(kSrc[i] + (size_t)kt * 64 * 64, kDst[i]);
            async16(vSrc[i] + (size_t)kt * 64,      vDst[i]);
        }
        __syncthreads();

        // S^T: A = K-frag (m = key), B = Q-frag (n = q) -> col = q = l32
        floatx16 s[2];
        __builtin_amdgcn_s_setprio(1);
#pragma unroll
        for (int nt = 0; nt < 2; nt++) {
            floatx16 cacc = {};
            int rowb = (nt * 32 + l32) * 8;
#pragma unroll
            for (int ks = 0; ks < 4; ks++) {
                short8 kf = *(const short8*)(Ks + (size_t)(rowb + ((ks * 2 + half) ^ sw)) * 8);
                cacc = __builtin_amdgcn_mfma_f32_32x32x16_bf16(kf, qf[ks], cacc, 0, 0, 0);
            }
            s[nt] = cacc;
        }
        __builtin_amdgcn_s_setprio(0);

        // exp2 + row-sum + pack P into A-fragments in registers:
        // reg (nt, r) -> pa[2*nt + (r>>3)], element j = r&7
        union { short8 s8; unsigned u[4]; } pa[4];
#pragma unroll
        for (int nt = 0; nt < 2; nt++)
#pragma unroll
            for (int r = 0; r < 16; r += 2) {
                float p0 = fast_exp2(s[nt][r]);
                float p1 = fast_exp2(s[nt][r + 1]);
                lsum += p0 + p1;
                pa[2 * nt + (r >> 3)].u[(r & 7) >> 1] = pack2bf(p0, p1);
            }

        // PV: A = P (registers), B = V^T tile (sigma key order)
        __builtin_amdgcn_s_setprio(1);
#pragma unroll
        for (int nt = 0; nt < 2; nt++) {
            int rowb = (nt * 32 + l32) * 8;
#pragma unroll
            for (int ks = 0; ks < 4; ks++) {
                short8 vf = *(const short8*)(Vs + (size_t)(rowb + ((ks * 2 + half) ^ sw)) * 8);
                acc[nt] = __builtin_amdgcn_mfma_f32_32x32x16_bf16(pa[ks].s8, vf, acc[nt], 0, 0, 0);
            }
        }
        __builtin_amdgcn_s_setprio(0);
    }

    // denominator for q = l32 (this lane's own q-row): combine the two halves
    float denom = lsum + __shfl_xor(lsum, 32);
    float inv_self = 1.0f / denom;

    int b_ = bh / 12, h = bh % 12;
#pragma unroll
    for (int nt = 0; nt < 2; nt++)
#pragma unroll
        for (int r = 0; r < 16; r++) {
            int qloc = (r & 3) + 8 * (r >> 2) + 4 * half;
            float invq = __shfl(inv_self, qloc);   // lane qloc holds q=qloc's inverse denom
            int q = qbase + qloc;
            int e = nt * 32 + l32;
            Ctx[((size_t)(b_ * 2048 + q)) * 768 + h * 64 + e] = f2bf(acc[nt][r] * invq);
        }
}

// ---------------- proj GEMM: out[8192,768] = Ctx @ W2^T + b, fp32 out ----------------
// Tile 64(M) x 128(N): 768 blocks = exactly 3/CU. XCD remap: XCD c owns M-rows [16c,16c+16).
__global__ __launch_bounds__(256) void gemm_out(
    const short* __restrict__ Ctx, const short* __restrict__ W,
    const float* __restrict__ bias, float* __restrict__ out)
{
    __shared__ short As[64 * 32];
    __shared__ short Bs[128 * 32];
    int tid = threadIdx.x;
    int w = tid >> 6, l = tid & 63;
    int lane16 = l & 15, quad = l >> 4;
    int wm = w & 1, wn = w >> 1;

    int fid = blockIdx.x + 6 * blockIdx.y;    // 0..767
    int c = fid & 7, s = fid >> 3;            // s in 0..95
    int my = c * 16 + s / 6;                  // 0..127
    int nx = s % 6;                           // 0..5
    int m0 = my * 64, n0 = nx * 128;

    floatx4 acc[2][4] = {};

    int srow = tid >> 2;        // 0..63
    int scol = (tid & 3) * 8;
    const short* Xg = Ctx + (size_t)(m0 + srow) * KDIM + scol;
    const short* Wg = W + (size_t)(n0 + srow) * KDIM + scol;
    short* AsW = As + (w * 16) * 32;
    short* BsW = Bs + (w * 16) * 32;

    for (int kb = 0; kb < KDIM; kb += 32) {
        __syncthreads();
        async16(Xg + kb,             AsW);
        async16(Wg + kb,             BsW);
        async16(Wg + kb + 64 * KDIM, BsW + 64 * 32);
        __syncthreads();
        short8 a[2], b[4];
#pragma unroll
        for (int mt = 0; mt < 2; mt++) a[mt] = *(const short8*)(As + (wm * 32 + mt * 16 + lane16) * 32 + quad * 8);
#pragma unroll
        for (int nt = 0; nt < 4; nt++) b[nt] = *(const short8*)(Bs + (wn * 64 + nt * 16 + lane16) * 32 + quad * 8);
#pragma unroll
        for (int mt = 0; mt < 2; mt++)
#pragma unroll
            for (int nt = 0; nt < 4; nt++)
                acc[mt][nt] = __builtin_amdgcn_mfma_f32_16x16x32_bf16(a[mt], b[nt], acc[mt][nt], 0, 0, 0);
    }

#pragma unroll
    for (int mt = 0; mt < 2; mt++) {
        int row = m0 + wm * 32 + mt * 16 + quad * 4;
#pragma unroll
        for (int nt = 0; nt < 4; nt++) {
            int col = n0 + wn * 64 + nt * 16 + lane16;
            float bv = bias[col];
#pragma unroll
            for (int r = 0; r < 4; r++)
                out[(size_t)(row + r) * 768 + col] = acc[mt][nt][r] + bv;
        }
    }
}

extern "C" void kernel_launch(void* const* d_in, const int* in_sizes, int n_in,
                              void* d_out, int out_size, void* d_ws, size_t ws_size,
                              hipStream_t stream) {
    const float* hs     = (const float*)d_in[0];
    const float* qkv_w  = (const float*)d_in[1];
    const float* qkv_b  = (const float*)d_in[2];
    const float* proj_w = (const float*)d_in[3];
    const float* proj_b = (const float*)d_in[4];
    float* out = (float*)d_out;

    short* Xb  = (short*)d_ws;                     // 8192*768 (dead after gemm_qkv; reused as Vt)
    short* W1b = Xb  + (size_t)8192 * 768;         // 2304*768
    short* W2b = W1b + (size_t)2304 * 768;         // 768*768
    short* Qb  = W2b + (size_t)768 * 768;          // 48*2048*64
    short* Kb  = Qb  + (size_t)8192 * 768;
    short* Vb  = Kb  + (size_t)8192 * 768;
    short* Ctx = Vb  + (size_t)8192 * 768;         // 8192*768
    short* Vt  = Xb;                               // [bh][64][2048] sigma-ordered, overlays dead Xb

    int ntot = (N1 + N2 + N3) / 4;
    cvt_all<<<(ntot + 255) / 256, 256, 0, stream>>>(hs, qkv_w, proj_w, Xb, W1b, W2b);

    gemm_qkv<<<dim3(18, 64), 256, 0, stream>>>(Xb, W1b, qkv_b, Qb, Kb, Vb);
    transpose_v<<<dim3(32, 48), 256, 0, stream>>>(Vb, Vt);
    attn<<<dim3(16, 48), 256, 0, stream>>>(Qb, Kb, Vt, Ctx);
    gemm_out<<<dim3(6, 128), 256, 0, stream>>>(Ctx, W2b, proj_b, out);
}